// Round 10
// baseline (554.001 us; speedup 1.0000x reference)
//
#include <hip/hip_runtime.h>
#include <hip/hip_bf16.h>

// v10: revert agg kernels to v7 proven shape (64-lane agg1, 32-lane final, 8-deep
// batches); NEW: k_scatter also materializes dinvE[pos] = dinv[src] so both agg
// kernels read their normalization weights as a SEQUENTIAL stream (no csr->dinv
// dependent random load). Exact same f32 bits, same FMA order -> bit-identical.
// dinvE needs +12.8MB: enabled only if ws_size >= 61MB, else exact v7 fallback.
// Launch fusion from v8 kept (k_init; scanB folded into scanC).

#define N_NODES 100000
#define N_EDGES 3200000
#define F_IN    128
#define H1F     64
#define H2F     32
#define NCLS    32
#define SCAN_BLOCK 1024
#define SCAN_CHUNKS ((N_NODES + SCAN_BLOCK - 1) / SCAN_BLOCK)   // 98
#define NTIL2 (N_NODES / 32)                                    // 3125 gemm tiles (32 nodes)
#define NCNT2 ((N_EDGES + 2048 - 1) / 2048)                     // 1563 count blocks (8 e/thr)
#define NFRONT (NTIL2 + NCNT2)                                  // 4688

typedef __attribute__((ext_vector_type(8))) short bf16x8;
typedef __attribute__((ext_vector_type(4))) float f32x4;

static __device__ __forceinline__ float b2f(__hip_bfloat16 v) {
    return __bfloat162float(v);
}
static __device__ __forceinline__ float us2f(unsigned short u) {
    return __uint_as_float(((unsigned)u) << 16);
}
static __device__ __forceinline__ unsigned short f2us(float f) {
    __hip_bfloat16 h = __float2bfloat16(f);
    return *(unsigned short*)&h;
}
static __device__ __forceinline__ float ld(const void* p, size_t i, int isbf) {
    return isbf ? b2f(((const __hip_bfloat16*)p)[i]) : ((const float*)p)[i];
}

// flags[0] = edge_index is int64 ; flags[1] = float tensors are bf16

// ---------------- init: zero deg + detect flags ----------------
__global__ void k_init(const void* xbuf, const void* eibuf, int* flags,
                       int* __restrict__ deg) {
    int t = blockIdx.x * blockDim.x + threadIdx.x;
    if (t < N_NODES) deg[t] = 0;
    if (blockIdx.x == 0 && threadIdx.x == 0) {
        const unsigned* ew = (const unsigned*)eibuf;
        int z = 0;
        for (int k = 0; k < 256; ++k) z += (ew[2 * k + 1] == 0u) ? 1 : 0;
        flags[0] = (z >= 200) ? 1 : 0;
        const unsigned* xw = (const unsigned*)xbuf;
        int inr = 0;
        for (int k = 0; k < 256; ++k) {
            unsigned fb = (xw[k] & 0xFFFFu) << 16;
            float a = fabsf(__uint_as_float(fb));
            inr += (a >= 1e-4f && a <= 20.0f) ? 1 : 0;
        }
        flags[1] = (inr >= 160) ? 1 : 0;
    }
}

// ---------------- FUSED front-end: gemm1 blocks interleaved with count blocks ----------
// blk%3==0 -> histogram+rank block (1563, 8 edges/thread)
// else     -> gemm1 tile block     (3125, 32 nodes: 8 nodes/wave, x via uniform s_load)
// Proven config (rounds 3/7/8/9): ~146us — count's atomic latency hides under gemm.
__global__ void __launch_bounds__(256)
k_front(const void* __restrict__ x, const void* __restrict__ W1,
        const int* __restrict__ ei,
        int* __restrict__ deg, int* __restrict__ aux,
        unsigned short* __restrict__ h1, const int* __restrict__ flags) {
    int blk = blockIdx.x, tid = threadIdx.x;

    if (blk % 3 == 0) {
        // -------- histogram + per-edge rank, 8 edges/thread --------
        int t = (blk / 3) * 256 + tid;
        int e0 = t * 8;
        if (e0 >= N_EDGES) return;
        int d[8];
        if (flags[0]) {
            const int4* p = (const int4*)(ei + 2 * (size_t)(N_EDGES + e0));
            int4 a = p[0], b = p[1], c = p[2], g = p[3];
            d[0] = a.x; d[1] = a.z; d[2] = b.x; d[3] = b.z;
            d[4] = c.x; d[5] = c.z; d[6] = g.x; d[7] = g.z;
        } else {
            const int4* p = (const int4*)(ei + (size_t)N_EDGES + e0);
            int4 a = p[0], b = p[1];
            d[0] = a.x; d[1] = a.y; d[2] = a.z; d[3] = a.w;
            d[4] = b.x; d[5] = b.y; d[6] = b.z; d[7] = b.w;
        }
        int r[8];
#pragma unroll
        for (int j = 0; j < 8; ++j)
            r[j] = ((unsigned)d[j] < N_NODES) ? atomicAdd(&deg[d[j]], 1) : 0;
        *(int4*)(aux + e0)     = make_int4(r[0], r[1], r[2], r[3]);
        *(int4*)(aux + e0 + 4) = make_int4(r[4], r[5], r[6], r[7]);
        return;
    }

    // -------- gemm1 tile: 32 nodes/block, 8 nodes/wave --------
    int tile = blk - blk / 3 - 1;                       // 0..3124, exact bijection
    int isbf = flags[1];
    int wave = __builtin_amdgcn_readfirstlane(tid >> 6);
    int lane = tid & 63;
    size_t nbase = (size_t)tile * 32 + (size_t)wave * 8;

    float acc[8];
#pragma unroll
    for (int i = 0; i < 8; ++i) acc[i] = 0.f;

    if (isbf) {
        const unsigned short* w  = (const unsigned short*)W1;
        const unsigned short* xp = (const unsigned short*)x;
#pragma unroll 4
        for (int k2 = 0; k2 < 64; ++k2) {
            float wa = us2f(w[(2 * k2) * H1F + lane]);
            float wb = us2f(w[(2 * k2 + 1) * H1F + lane]);
#pragma unroll
            for (int i = 0; i < 8; ++i) {
                float xa = us2f(xp[(nbase + i) * F_IN + 2 * k2]);
                float xb = us2f(xp[(nbase + i) * F_IN + 2 * k2 + 1]);
                acc[i] += xa * wa;
                acc[i] += xb * wb;
            }
        }
    } else {
        const float* w  = (const float*)W1;
        const float* xp = (const float*)x;
#pragma unroll 4
        for (int k2 = 0; k2 < 64; ++k2) {
            float wa = w[(2 * k2) * H1F + lane];
            float wb = w[(2 * k2 + 1) * H1F + lane];
#pragma unroll
            for (int i = 0; i < 8; ++i) {
                float xa = xp[(nbase + i) * F_IN + 2 * k2];
                float xb = xp[(nbase + i) * F_IN + 2 * k2 + 1];
                acc[i] += xa * wa;
                acc[i] += xb * wb;
            }
        }
    }

#pragma unroll
    for (int i = 0; i < 8; ++i)
        h1[(nbase + i) * H1F + lane] = f2us(acc[i]);
}

__global__ void k_scanA(const int* __restrict__ deg, int* __restrict__ partial,
                        float* __restrict__ dinv) {
    __shared__ int red[16];
    int b = blockIdx.x, t = threadIdx.x;
    int i = b * SCAN_BLOCK + t;
    int v = (i < N_NODES) ? deg[i] : 0;
    if (i < N_NODES) dinv[i] = rsqrtf((float)v + 1.0f);  // +1 self-loop (fused k_dinv)
    for (int off = 32; off; off >>= 1) v += __shfl_down(v, off, 64);
    if ((t & 63) == 0) red[t >> 6] = v;
    __syncthreads();
    if (t == 0) {
        int s = 0;
        for (int k = 0; k < 16; ++k) s += red[k];
        partial[b] = s;
    }
}

// scanC with scanB folded in: each block computes its own chunk offset by a parallel
// reduction of partial[0..b-1] (<=98 ints), then does the intra-chunk scan.
__global__ void k_scanC(const int* __restrict__ deg, const int* __restrict__ partial,
                        int* __restrict__ rowptr) {
    __shared__ int wsum[16];
    __shared__ int red[16];
    int b = blockIdx.x, t = threadIdx.x, lane = t & 63, w = t >> 6;
    int i = b * SCAN_BLOCK + t;
    int c = (t < SCAN_CHUNKS && t < b) ? partial[t] : 0;
    for (int off = 32; off; off >>= 1) c += __shfl_down(c, off, 64);
    if (lane == 0) red[w] = c;
    int v = (i < N_NODES) ? deg[i] : 0;
    for (int off = 1; off < 64; off <<= 1) {
        int u = __shfl_up(v, off, 64);
        if (lane >= off) v += u;
    }
    if (lane == 63) wsum[w] = v;
    __syncthreads();
    if (t == 0) {
        int run = 0;
        for (int k = 0; k < 16; ++k) { int s = wsum[k]; wsum[k] = run; run += s; }
        int sc = 0;
        for (int k = 0; k < 16; ++k) sc += red[k];
        red[0] = sc;                                    // chunk offset broadcast
    }
    __syncthreads();
    int incl = v + wsum[w] + red[0];
    if (i < N_NODES) rowptr[i + 1] = incl;
    if (b == 0 && t == 0) rowptr[0] = 0;
}

// atomic-free CSR fill; 8 edges/thread, batched rowptr gathers.
// If dinvE != null, also materialize dinvE[pos] = dinv[src] (exact f32 bits) so the
// agg kernels read weights as a sequential stream.
__global__ void __launch_bounds__(256)
k_scatter(const int* __restrict__ ei, const int* __restrict__ aux,
          const int* __restrict__ rowptr, const float* __restrict__ dinv,
          int* __restrict__ csr, float* __restrict__ dinvE,
          const int* __restrict__ flags) {
    int t = blockIdx.x * blockDim.x + threadIdx.x;
    int e0 = t * 8;
    if (e0 >= N_EDGES) return;
    int s[8], d[8];
    if (flags[0]) {
        const int4* ps = (const int4*)(ei + 2 * (size_t)e0);
#pragma unroll
        for (int q = 0; q < 4; ++q) {
            int4 a = ps[q];
            s[2 * q] = a.x; s[2 * q + 1] = a.z;
        }
        const int4* pd = (const int4*)(ei + 2 * (size_t)(N_EDGES + e0));
#pragma unroll
        for (int q = 0; q < 4; ++q) {
            int4 c = pd[q];
            d[2 * q] = c.x; d[2 * q + 1] = c.z;
        }
    } else {
        const int4* ps = (const int4*)(ei + (size_t)e0);
#pragma unroll
        for (int q = 0; q < 2; ++q) {
            int4 a = ps[q];
            s[4 * q] = a.x; s[4 * q + 1] = a.y; s[4 * q + 2] = a.z; s[4 * q + 3] = a.w;
        }
        const int4* pd = (const int4*)(ei + (size_t)N_EDGES + e0);
#pragma unroll
        for (int q = 0; q < 2; ++q) {
            int4 c = pd[q];
            d[4 * q] = c.x; d[4 * q + 1] = c.y; d[4 * q + 2] = c.z; d[4 * q + 3] = c.w;
        }
    }
    int a8[8];
    {
        int4 av0 = *(const int4*)(aux + e0);
        int4 av1 = *(const int4*)(aux + e0 + 4);
        a8[0] = av0.x; a8[1] = av0.y; a8[2] = av0.z; a8[3] = av0.w;
        a8[4] = av1.x; a8[5] = av1.y; a8[6] = av1.z; a8[7] = av1.w;
    }
    int rp[8];
#pragma unroll
    for (int j = 0; j < 8; ++j) {
        bool ok = (unsigned)s[j] < N_NODES && (unsigned)d[j] < N_NODES;
        rp[j] = ok ? rowptr[d[j]] : -1;
    }
    if (dinvE) {
        float dv[8];
#pragma unroll
        for (int j = 0; j < 8; ++j) dv[j] = (rp[j] >= 0) ? dinv[s[j]] : 0.f;
#pragma unroll
        for (int j = 0; j < 8; ++j) {
            if (rp[j] >= 0) {
                int pos = rp[j] + a8[j];
                csr[pos]   = s[j];
                dinvE[pos] = dv[j];
            }
        }
    } else {
#pragma unroll
        for (int j = 0; j < 8; ++j) {
            if (rp[j] >= 0) csr[rp[j] + a8[j]] = s[j];
        }
    }
}

// ---------------- fused agg1 + bias/ReLU + GEMM2 -> h2(bf16) ; wave per node ----------------
// v7 proven shape. dE (if non-null) supplies weights sequentially (bit-identical values).
__global__ void k_agg1gemm2(const unsigned short* __restrict__ h1,
                            const float* __restrict__ dinv,
                            const float* __restrict__ dE,
                            const int* __restrict__ rowptr, const int* __restrict__ csr,
                            const void* __restrict__ b1, const void* __restrict__ W2,
                            unsigned short* __restrict__ h2, const int* __restrict__ flags) {
    int n    = (blockIdx.x * blockDim.x + threadIdx.x) >> 6;
    n = __builtin_amdgcn_readfirstlane(n);
    int lane = threadIdx.x & 63;
    if (n >= N_NODES) return;
    int beg = rowptr[n], end = rowptr[n + 1];
    float dn  = dinv[n];
    float acc = dn * us2f(h1[(size_t)n * H1F + lane]);  // self-loop
    int e = beg;
    if (dE) {
        for (; e + 7 < end; e += 8) {
            int s0 = csr[e],     s1 = csr[e + 1], s2 = csr[e + 2], s3 = csr[e + 3];
            int s4 = csr[e + 4], s5 = csr[e + 5], s6 = csr[e + 6], s7 = csr[e + 7];
            float w0 = dE[e],     w1 = dE[e + 1], w2 = dE[e + 2], w3 = dE[e + 3];
            float w4 = dE[e + 4], w5 = dE[e + 5], w6 = dE[e + 6], w7 = dE[e + 7];
            unsigned short v0 = h1[(size_t)s0 * H1F + lane];
            unsigned short v1 = h1[(size_t)s1 * H1F + lane];
            unsigned short v2 = h1[(size_t)s2 * H1F + lane];
            unsigned short v3 = h1[(size_t)s3 * H1F + lane];
            unsigned short v4 = h1[(size_t)s4 * H1F + lane];
            unsigned short v5 = h1[(size_t)s5 * H1F + lane];
            unsigned short v6 = h1[(size_t)s6 * H1F + lane];
            unsigned short v7 = h1[(size_t)s7 * H1F + lane];
            acc += w0 * us2f(v0); acc += w1 * us2f(v1);
            acc += w2 * us2f(v2); acc += w3 * us2f(v3);
            acc += w4 * us2f(v4); acc += w5 * us2f(v5);
            acc += w6 * us2f(v6); acc += w7 * us2f(v7);
        }
        for (; e < end; ++e) {
            int s = csr[e];
            acc += dE[e] * us2f(h1[(size_t)s * H1F + lane]);
        }
    } else {
        for (; e + 7 < end; e += 8) {
            int s0 = csr[e],     s1 = csr[e + 1], s2 = csr[e + 2], s3 = csr[e + 3];
            int s4 = csr[e + 4], s5 = csr[e + 5], s6 = csr[e + 6], s7 = csr[e + 7];
            float w0 = dinv[s0], w1 = dinv[s1], w2 = dinv[s2], w3 = dinv[s3];
            float w4 = dinv[s4], w5 = dinv[s5], w6 = dinv[s6], w7 = dinv[s7];
            unsigned short v0 = h1[(size_t)s0 * H1F + lane];
            unsigned short v1 = h1[(size_t)s1 * H1F + lane];
            unsigned short v2 = h1[(size_t)s2 * H1F + lane];
            unsigned short v3 = h1[(size_t)s3 * H1F + lane];
            unsigned short v4 = h1[(size_t)s4 * H1F + lane];
            unsigned short v5 = h1[(size_t)s5 * H1F + lane];
            unsigned short v6 = h1[(size_t)s6 * H1F + lane];
            unsigned short v7 = h1[(size_t)s7 * H1F + lane];
            acc += w0 * us2f(v0); acc += w1 * us2f(v1);
            acc += w2 * us2f(v2); acc += w3 * us2f(v3);
            acc += w4 * us2f(v4); acc += w5 * us2f(v5);
            acc += w6 * us2f(v6); acc += w7 * us2f(v7);
        }
        for (; e < end; ++e) {
            int s = csr[e];
            acc += dinv[s] * us2f(h1[(size_t)s * H1F + lane]);
        }
    }
    acc *= dn;                                          // agg1[n][lane]
    int isbf = flags[1];
    float bv = isbf ? b2f(((const __hip_bfloat16*)b1)[lane]) : ((const float*)b1)[lane];
    float v  = fmaxf(acc + bv, 0.f);                    // relu(agg1 + b1)
    int f = lane & 31, h = lane >> 5;
    float part = 0.f;
    if (isbf) {
        const __hip_bfloat16* w = (const __hip_bfloat16*)W2;
#pragma unroll
        for (int j = 0; j < 32; ++j) {
            int k = h * 32 + j;
            part += __shfl(v, k, 64) * b2f(w[k * H2F + f]);
        }
    } else {
        const float* w = (const float*)W2;
#pragma unroll
        for (int j = 0; j < 32; ++j) {
            int k = h * 32 + j;
            part += __shfl(v, k, 64) * w[k * H2F + f];
        }
    }
    part += __shfl(part, lane ^ 32, 64);                // combine halves
    if (h == 0) h2[(size_t)n * H2F + f] = f2us(part);
}

// ---------------- fused agg2 + final MLP -> out ; half-wave per node ----------------
__global__ void GCN_51737176048479_kernel(const unsigned short* __restrict__ h2,
                                          const float* __restrict__ dinv,
                                          const float* __restrict__ dE,
                                          const int* __restrict__ rowptr,
                                          const int* __restrict__ csr,
                                          const void* __restrict__ b2v,
                                          const void* __restrict__ Wf,
                                          const void* __restrict__ bfv,
                                          const void* __restrict__ Wo,
                                          const void* __restrict__ bov,
                                          void* __restrict__ out,
                                          const int* __restrict__ flags) {
    int tid = blockIdx.x * blockDim.x + threadIdx.x;
    int n   = tid >> 5;
    int f   = threadIdx.x & 31;
    if (n >= N_NODES) return;
    int isbf = flags[1];
    int beg = rowptr[n], end = rowptr[n + 1];
    float dn = dinv[n];
    float ar = dn * us2f(h2[(size_t)n * H2F + f]);
    int e = beg;
    if (dE) {
        for (; e + 7 < end; e += 8) {
            int s0 = csr[e],     s1 = csr[e + 1], s2 = csr[e + 2], s3 = csr[e + 3];
            int s4 = csr[e + 4], s5 = csr[e + 5], s6 = csr[e + 6], s7 = csr[e + 7];
            float w0 = dE[e],     w1 = dE[e + 1], w2 = dE[e + 2], w3 = dE[e + 3];
            float w4 = dE[e + 4], w5 = dE[e + 5], w6 = dE[e + 6], w7 = dE[e + 7];
            unsigned short v0 = h2[(size_t)s0 * H2F + f];
            unsigned short v1 = h2[(size_t)s1 * H2F + f];
            unsigned short v2 = h2[(size_t)s2 * H2F + f];
            unsigned short v3 = h2[(size_t)s3 * H2F + f];
            unsigned short v4 = h2[(size_t)s4 * H2F + f];
            unsigned short v5 = h2[(size_t)s5 * H2F + f];
            unsigned short v6 = h2[(size_t)s6 * H2F + f];
            unsigned short v7 = h2[(size_t)s7 * H2F + f];
            ar += w0 * us2f(v0); ar += w1 * us2f(v1);
            ar += w2 * us2f(v2); ar += w3 * us2f(v3);
            ar += w4 * us2f(v4); ar += w5 * us2f(v5);
            ar += w6 * us2f(v6); ar += w7 * us2f(v7);
        }
        for (; e < end; ++e) {
            int s = csr[e];
            ar += dE[e] * us2f(h2[(size_t)s * H2F + f]);
        }
    } else {
        for (; e + 7 < end; e += 8) {
            int s0 = csr[e],     s1 = csr[e + 1], s2 = csr[e + 2], s3 = csr[e + 3];
            int s4 = csr[e + 4], s5 = csr[e + 5], s6 = csr[e + 6], s7 = csr[e + 7];
            float w0 = dinv[s0], w1 = dinv[s1], w2 = dinv[s2], w3 = dinv[s3];
            float w4 = dinv[s4], w5 = dinv[s5], w6 = dinv[s6], w7 = dinv[s7];
            unsigned short v0 = h2[(size_t)s0 * H2F + f];
            unsigned short v1 = h2[(size_t)s1 * H2F + f];
            unsigned short v2 = h2[(size_t)s2 * H2F + f];
            unsigned short v3 = h2[(size_t)s3 * H2F + f];
            unsigned short v4 = h2[(size_t)s4 * H2F + f];
            unsigned short v5 = h2[(size_t)s5 * H2F + f];
            unsigned short v6 = h2[(size_t)s6 * H2F + f];
            unsigned short v7 = h2[(size_t)s7 * H2F + f];
            ar += w0 * us2f(v0); ar += w1 * us2f(v1);
            ar += w2 * us2f(v2); ar += w3 * us2f(v3);
            ar += w4 * us2f(v4); ar += w5 * us2f(v5);
            ar += w6 * us2f(v6); ar += w7 * us2f(v7);
        }
        for (; e < end; ++e) {
            int s = csr[e];
            ar += dinv[s] * us2f(h2[(size_t)s * H2F + f]);
        }
    }
    ar = ar * dn + ld(b2v, f, isbf);                    // conv2 out (no relu)
    float acc1 = 0.f;
#pragma unroll
    for (int k = 0; k < H2F; ++k)
        acc1 += __shfl(ar, k, 32) * ld(Wf, (size_t)k * H2F + f, isbf);
    float u = fmaxf(acc1 + ld(bfv, f, isbf), 0.f);
    float acc2 = 0.f;
#pragma unroll
    for (int k = 0; k < H2F; ++k)
        acc2 += __shfl(u, k, 32) * ld(Wo, (size_t)k * NCLS + f, isbf);
    float r = acc2 + ld(bov, f, isbf);
    size_t oi = (size_t)n * NCLS + f;
    if (isbf) ((__hip_bfloat16*)out)[oi] = __float2bfloat16(r);
    else      ((float*)out)[oi] = r;
}

extern "C" void kernel_launch(void* const* d_in, const int* in_sizes, int n_in,
                              void* d_out, int out_size, void* d_ws, size_t ws_size,
                              hipStream_t stream) {
    const void* x  = d_in[0];
    const int*  ei = (const int*)d_in[1];
    const void* W1 = d_in[2];
    const void* b1 = d_in[3];
    const void* W2 = d_in[4];
    const void* b2 = d_in[5];
    const void* Wf = d_in[6];
    const void* bf = d_in[7];
    const void* Wo = d_in[8];
    const void* bo = d_in[9];

    // layout A (ws >= 61MB): deg@0 | rowptr@512K | dinv@1M | flags@1.4M | partial@1.41M
    //   aux@2M(12.8) | csr@15M(12.8) | dinvE@28M(12.8) | h1@41M(12.8) | h2@54M(6.4) = 60.4M
    // layout B (fallback, v7):  ... | aux@2M | csr@15M | h1@28M | h2@41M = 47.4M
    char* ws = (char*)d_ws;
    int*            deg      = (int*)  (ws + 0);
    int*            rowptr   = (int*)  (ws + (512u  << 10));
    float*          dinv     = (float*)(ws + (1024u << 10));
    int*            flags    = (int*)  (ws + (1434u << 10));
    int*            partial  = (int*)  (ws + (1444u << 10));
    int*            aux      = (int*)  (ws + (2u  << 20));
    int*            csr      = (int*)  (ws + (15u << 20));
    int use_de = (ws_size >= (61ull << 20)) ? 1 : 0;
    float*          dinvE    = use_de ? (float*)(ws + (28u << 20)) : (float*)0;
    unsigned short* h1       = (unsigned short*)(ws + ((use_de ? 41u : 28u) << 20));
    unsigned short* h2       = (unsigned short*)(ws + ((use_de ? 54u : 41u) << 20));

    const int B = 256;

    k_init<<<SCAN_CHUNKS, SCAN_BLOCK, 0, stream>>>(x, ei, flags, deg);

    // fused gemm1 + histogram (independent work, interleaved for co-residency)
    k_front<<<NFRONT, B, 0, stream>>>(x, W1, ei, deg, aux, h1, flags);

    k_scanA<<<SCAN_CHUNKS, SCAN_BLOCK, 0, stream>>>(deg, partial, dinv);
    k_scanC<<<SCAN_CHUNKS, SCAN_BLOCK, 0, stream>>>(deg, partial, rowptr);
    k_scatter<<<(N_EDGES / 8 + B - 1) / B, B, 0, stream>>>(ei, aux, rowptr, dinv,
                                                           csr, dinvE, flags);

    k_agg1gemm2<<<(N_NODES * 64 + B - 1) / B, B, 0, stream>>>(h1, dinv, dinvE, rowptr,
                                                              csr, b1, W2, h2, flags);
    GCN_51737176048479_kernel<<<(N_NODES * 32 + B - 1) / B, B, 0, stream>>>(
        h2, dinv, dinvE, rowptr, csr, b2, Wf, bf, Wo, bo, d_out, flags);
}

// Round 11
// 501.098 us; speedup vs baseline: 1.1056x; 1.1056x over previous
//
#include <hip/hip_runtime.h>
#include <hip/hip_bf16.h>

// v11 == v7 (measured session-best: 501.7us). Locks in the proven configuration:
// - k_front: 1:2 interleaved count(8e/thr, returning atomics)/gemm1(s_load, 8 nodes/wave)
// - 3-phase scan + dinv fused into scanA
// - k_scatter: 8 e/thr, batched rowptr gathers
// - agg kernels: v5 csr-batch prefetch, 64-lane agg1 / 32-lane final
// Post-v7 experiments (launch fusion, 2-level pipeline, paired-feature lanes,
// dinvE weight streaming) all measured neutral-to-negative and are reverted.

#define N_NODES 100000
#define N_EDGES 3200000
#define F_IN    128
#define H1F     64
#define H2F     32
#define NCLS    32
#define SCAN_BLOCK 1024
#define SCAN_CHUNKS ((N_NODES + SCAN_BLOCK - 1) / SCAN_BLOCK)   // 98
#define NTIL2 (N_NODES / 32)                                    // 3125 gemm tiles (32 nodes)
#define NCNT2 ((N_EDGES + 2048 - 1) / 2048)                     // 1563 count blocks (8 e/thr)
#define NFRONT (NTIL2 + NCNT2)                                  // 4688

typedef __attribute__((ext_vector_type(8))) short bf16x8;
typedef __attribute__((ext_vector_type(4))) float f32x4;

static __device__ __forceinline__ float b2f(__hip_bfloat16 v) {
    return __bfloat162float(v);
}
static __device__ __forceinline__ float us2f(unsigned short u) {
    return __uint_as_float(((unsigned)u) << 16);
}
static __device__ __forceinline__ unsigned short f2us(float f) {
    __hip_bfloat16 h = __float2bfloat16(f);
    return *(unsigned short*)&h;
}
static __device__ __forceinline__ float ld(const void* p, size_t i, int isbf) {
    return isbf ? b2f(((const __hip_bfloat16*)p)[i]) : ((const float*)p)[i];
}

// flags[0] = edge_index is int64 ; flags[1] = float tensors are bf16

__global__ void k_detect(const void* xbuf, const void* eibuf, int* flags) {
    if (threadIdx.x != 0 || blockIdx.x != 0) return;
    const unsigned* ew = (const unsigned*)eibuf;
    int z = 0;
    for (int k = 0; k < 256; ++k) z += (ew[2 * k + 1] == 0u) ? 1 : 0;
    flags[0] = (z >= 200) ? 1 : 0;
    const unsigned* xw = (const unsigned*)xbuf;
    int inr = 0;
    for (int k = 0; k < 256; ++k) {
        unsigned fb = (xw[k] & 0xFFFFu) << 16;
        float a = fabsf(__uint_as_float(fb));
        inr += (a >= 1e-4f && a <= 20.0f) ? 1 : 0;
    }
    flags[1] = (inr >= 160) ? 1 : 0;
}

// ---------------- FUSED front-end: gemm1 blocks interleaved with count blocks ----------
// blk%3==0 -> histogram+rank block (1563, 8 edges/thread)
// else     -> gemm1 tile block     (3125, 32 nodes: 8 nodes/wave, x via uniform s_load)
// Proven config (rounds 3/7): ~147us — count's atomic latency hides under co-resident gemm.
__global__ void __launch_bounds__(256)
k_front(const void* __restrict__ x, const void* __restrict__ W1,
        const int* __restrict__ ei,
        int* __restrict__ deg, int* __restrict__ aux,
        unsigned short* __restrict__ h1, const int* __restrict__ flags) {
    int blk = blockIdx.x, tid = threadIdx.x;

    if (blk % 3 == 0) {
        // -------- histogram + per-edge rank, 8 edges/thread --------
        int t = (blk / 3) * 256 + tid;
        int e0 = t * 8;
        if (e0 >= N_EDGES) return;
        int d[8];
        if (flags[0]) {
            const int4* p = (const int4*)(ei + 2 * (size_t)(N_EDGES + e0));
            int4 a = p[0], b = p[1], c = p[2], g = p[3];
            d[0] = a.x; d[1] = a.z; d[2] = b.x; d[3] = b.z;
            d[4] = c.x; d[5] = c.z; d[6] = g.x; d[7] = g.z;
        } else {
            const int4* p = (const int4*)(ei + (size_t)N_EDGES + e0);
            int4 a = p[0], b = p[1];
            d[0] = a.x; d[1] = a.y; d[2] = a.z; d[3] = a.w;
            d[4] = b.x; d[5] = b.y; d[6] = b.z; d[7] = b.w;
        }
        int r[8];
#pragma unroll
        for (int j = 0; j < 8; ++j)
            r[j] = ((unsigned)d[j] < N_NODES) ? atomicAdd(&deg[d[j]], 1) : 0;
        *(int4*)(aux + e0)     = make_int4(r[0], r[1], r[2], r[3]);
        *(int4*)(aux + e0 + 4) = make_int4(r[4], r[5], r[6], r[7]);
        return;
    }

    // -------- gemm1 tile: 32 nodes/block, 8 nodes/wave --------
    int tile = blk - blk / 3 - 1;                       // 0..3124, exact bijection
    int isbf = flags[1];
    int wave = __builtin_amdgcn_readfirstlane(tid >> 6);
    int lane = tid & 63;
    size_t nbase = (size_t)tile * 32 + (size_t)wave * 8;

    float acc[8];
#pragma unroll
    for (int i = 0; i < 8; ++i) acc[i] = 0.f;

    if (isbf) {
        const unsigned short* w  = (const unsigned short*)W1;
        const unsigned short* xp = (const unsigned short*)x;
#pragma unroll 4
        for (int k2 = 0; k2 < 64; ++k2) {
            float wa = us2f(w[(2 * k2) * H1F + lane]);
            float wb = us2f(w[(2 * k2 + 1) * H1F + lane]);
#pragma unroll
            for (int i = 0; i < 8; ++i) {
                float xa = us2f(xp[(nbase + i) * F_IN + 2 * k2]);
                float xb = us2f(xp[(nbase + i) * F_IN + 2 * k2 + 1]);
                acc[i] += xa * wa;
                acc[i] += xb * wb;
            }
        }
    } else {
        const float* w  = (const float*)W1;
        const float* xp = (const float*)x;
#pragma unroll 4
        for (int k2 = 0; k2 < 64; ++k2) {
            float wa = w[(2 * k2) * H1F + lane];
            float wb = w[(2 * k2 + 1) * H1F + lane];
#pragma unroll
            for (int i = 0; i < 8; ++i) {
                float xa = xp[(nbase + i) * F_IN + 2 * k2];
                float xb = xp[(nbase + i) * F_IN + 2 * k2 + 1];
                acc[i] += xa * wa;
                acc[i] += xb * wb;
            }
        }
    }

#pragma unroll
    for (int i = 0; i < 8; ++i)
        h1[(nbase + i) * H1F + lane] = f2us(acc[i]);
}

__global__ void k_scanA(const int* __restrict__ deg, int* __restrict__ partial,
                        float* __restrict__ dinv) {
    __shared__ int red[16];
    int b = blockIdx.x, t = threadIdx.x;
    int i = b * SCAN_BLOCK + t;
    int v = (i < N_NODES) ? deg[i] : 0;
    if (i < N_NODES) dinv[i] = rsqrtf((float)v + 1.0f);  // +1 self-loop (fused k_dinv)
    for (int off = 32; off; off >>= 1) v += __shfl_down(v, off, 64);
    if ((t & 63) == 0) red[t >> 6] = v;
    __syncthreads();
    if (t == 0) {
        int s = 0;
        for (int k = 0; k < 16; ++k) s += red[k];
        partial[b] = s;
    }
}

__global__ void k_scanB(const int* __restrict__ partial, int* __restrict__ chunkoff) {
    if (threadIdx.x != 0 || blockIdx.x != 0) return;
    int run = 0;
    for (int b = 0; b < SCAN_CHUNKS; ++b) { chunkoff[b] = run; run += partial[b]; }
}

__global__ void k_scanC(const int* __restrict__ deg, const int* __restrict__ chunkoff,
                        int* __restrict__ rowptr) {
    __shared__ int wsum[16];
    int b = blockIdx.x, t = threadIdx.x, lane = t & 63, w = t >> 6;
    int i = b * SCAN_BLOCK + t;
    int v = (i < N_NODES) ? deg[i] : 0;
    for (int off = 1; off < 64; off <<= 1) {
        int u = __shfl_up(v, off, 64);
        if (lane >= off) v += u;
    }
    if (lane == 63) wsum[w] = v;
    __syncthreads();
    if (t == 0) {
        int run = 0;
        for (int k = 0; k < 16; ++k) { int s = wsum[k]; wsum[k] = run; run += s; }
    }
    __syncthreads();
    int incl = v + wsum[w] + chunkoff[b];
    if (i < N_NODES) rowptr[i + 1] = incl;
    if (b == 0 && t == 0) rowptr[0] = 0;
}

// atomic-free CSR fill using precomputed ranks; 8 edges/thread, batched rowptr gathers
__global__ void __launch_bounds__(256)
k_scatter(const int* __restrict__ ei, const int* __restrict__ aux,
          const int* __restrict__ rowptr, int* __restrict__ csr,
          const int* __restrict__ flags) {
    int t = blockIdx.x * blockDim.x + threadIdx.x;
    int e0 = t * 8;
    if (e0 >= N_EDGES) return;
    int s[8], d[8];
    if (flags[0]) {
        const int4* ps = (const int4*)(ei + 2 * (size_t)e0);
#pragma unroll
        for (int q = 0; q < 4; ++q) {
            int4 a = ps[q];
            s[2 * q] = a.x; s[2 * q + 1] = a.z;
        }
        const int4* pd = (const int4*)(ei + 2 * (size_t)(N_EDGES + e0));
#pragma unroll
        for (int q = 0; q < 4; ++q) {
            int4 c = pd[q];
            d[2 * q] = c.x; d[2 * q + 1] = c.z;
        }
    } else {
        const int4* ps = (const int4*)(ei + (size_t)e0);
#pragma unroll
        for (int q = 0; q < 2; ++q) {
            int4 a = ps[q];
            s[4 * q] = a.x; s[4 * q + 1] = a.y; s[4 * q + 2] = a.z; s[4 * q + 3] = a.w;
        }
        const int4* pd = (const int4*)(ei + (size_t)N_EDGES + e0);
#pragma unroll
        for (int q = 0; q < 2; ++q) {
            int4 c = pd[q];
            d[4 * q] = c.x; d[4 * q + 1] = c.y; d[4 * q + 2] = c.z; d[4 * q + 3] = c.w;
        }
    }
    int a8[8];
    {
        int4 av0 = *(const int4*)(aux + e0);
        int4 av1 = *(const int4*)(aux + e0 + 4);
        a8[0] = av0.x; a8[1] = av0.y; a8[2] = av0.z; a8[3] = av0.w;
        a8[4] = av1.x; a8[5] = av1.y; a8[6] = av1.z; a8[7] = av1.w;
    }
    // batch the random rowptr gathers (independent, 8 in flight)
    int rp[8];
#pragma unroll
    for (int j = 0; j < 8; ++j) {
        bool ok = (unsigned)s[j] < N_NODES && (unsigned)d[j] < N_NODES;
        rp[j] = ok ? rowptr[d[j]] : -1;
    }
#pragma unroll
    for (int j = 0; j < 8; ++j) {
        if (rp[j] >= 0) csr[rp[j] + a8[j]] = s[j];
    }
}

// ---------------- fused agg1 + bias/ReLU + GEMM2 -> h2(bf16) ; wave per node ----------------
__global__ void k_agg1gemm2(const unsigned short* __restrict__ h1,
                            const float* __restrict__ dinv,
                            const int* __restrict__ rowptr, const int* __restrict__ csr,
                            const void* __restrict__ b1, const void* __restrict__ W2,
                            unsigned short* __restrict__ h2, const int* __restrict__ flags) {
    int n    = (blockIdx.x * blockDim.x + threadIdx.x) >> 6;
    n = __builtin_amdgcn_readfirstlane(n);
    int lane = threadIdx.x & 63;
    if (n >= N_NODES) return;
    int beg = rowptr[n], end = rowptr[n + 1];
    float dn  = dinv[n];
    float acc = dn * us2f(h1[(size_t)n * H1F + lane]);  // self-loop
    int e = beg;
    int nfull = (end - beg) >> 3;
    if (nfull > 0) {
        int sn[8];
#pragma unroll
        for (int j = 0; j < 8; ++j) sn[j] = csr[e + j];
        for (int b = 0; b < nfull; ++b) {
            int sc[8];
#pragma unroll
            for (int j = 0; j < 8; ++j) sc[j] = sn[j];
            e += 8;
            if (b + 1 < nfull) {
#pragma unroll
                for (int j = 0; j < 8; ++j) sn[j] = csr[e + j];   // prefetch next batch
            }
            float w0 = dinv[sc[0]], w1 = dinv[sc[1]], w2 = dinv[sc[2]], w3 = dinv[sc[3]];
            float w4 = dinv[sc[4]], w5 = dinv[sc[5]], w6 = dinv[sc[6]], w7 = dinv[sc[7]];
            unsigned short v0 = h1[(size_t)sc[0] * H1F + lane];
            unsigned short v1 = h1[(size_t)sc[1] * H1F + lane];
            unsigned short v2 = h1[(size_t)sc[2] * H1F + lane];
            unsigned short v3 = h1[(size_t)sc[3] * H1F + lane];
            unsigned short v4 = h1[(size_t)sc[4] * H1F + lane];
            unsigned short v5 = h1[(size_t)sc[5] * H1F + lane];
            unsigned short v6 = h1[(size_t)sc[6] * H1F + lane];
            unsigned short v7 = h1[(size_t)sc[7] * H1F + lane];
            acc += w0 * us2f(v0); acc += w1 * us2f(v1);
            acc += w2 * us2f(v2); acc += w3 * us2f(v3);
            acc += w4 * us2f(v4); acc += w5 * us2f(v5);
            acc += w6 * us2f(v6); acc += w7 * us2f(v7);
        }
    }
    for (; e + 3 < end; e += 4) {
        int s0 = csr[e], s1 = csr[e + 1], s2 = csr[e + 2], s3 = csr[e + 3];
        float w0 = dinv[s0], w1 = dinv[s1], w2 = dinv[s2], w3 = dinv[s3];
        unsigned short v0 = h1[(size_t)s0 * H1F + lane];
        unsigned short v1 = h1[(size_t)s1 * H1F + lane];
        unsigned short v2 = h1[(size_t)s2 * H1F + lane];
        unsigned short v3 = h1[(size_t)s3 * H1F + lane];
        acc += w0 * us2f(v0); acc += w1 * us2f(v1);
        acc += w2 * us2f(v2); acc += w3 * us2f(v3);
    }
    for (; e < end; ++e) {
        int s = csr[e];
        acc += dinv[s] * us2f(h1[(size_t)s * H1F + lane]);
    }
    acc *= dn;                                          // agg1[n][lane]
    int isbf = flags[1];
    float bv = isbf ? b2f(((const __hip_bfloat16*)b1)[lane]) : ((const float*)b1)[lane];
    float v  = fmaxf(acc + bv, 0.f);                    // relu(agg1 + b1)
    int f = lane & 31, h = lane >> 5;
    float part = 0.f;
    if (isbf) {
        const __hip_bfloat16* w = (const __hip_bfloat16*)W2;
#pragma unroll
        for (int j = 0; j < 32; ++j) {
            int k = h * 32 + j;
            part += __shfl(v, k, 64) * b2f(w[k * H2F + f]);
        }
    } else {
        const float* w = (const float*)W2;
#pragma unroll
        for (int j = 0; j < 32; ++j) {
            int k = h * 32 + j;
            part += __shfl(v, k, 64) * w[k * H2F + f];
        }
    }
    part += __shfl(part, lane ^ 32, 64);                // combine halves
    if (h == 0) h2[(size_t)n * H2F + f] = f2us(part);
}

// ---------------- fused agg2 + final MLP -> out ; half-wave per node ----------------
__global__ void GCN_51737176048479_kernel(const unsigned short* __restrict__ h2,
                                          const float* __restrict__ dinv,
                                          const int* __restrict__ rowptr,
                                          const int* __restrict__ csr,
                                          const void* __restrict__ b2v,
                                          const void* __restrict__ Wf,
                                          const void* __restrict__ bfv,
                                          const void* __restrict__ Wo,
                                          const void* __restrict__ bov,
                                          void* __restrict__ out,
                                          const int* __restrict__ flags) {
    int tid = blockIdx.x * blockDim.x + threadIdx.x;
    int n   = tid >> 5;
    int f   = threadIdx.x & 31;
    if (n >= N_NODES) return;
    int isbf = flags[1];
    int beg = rowptr[n], end = rowptr[n + 1];
    float dn = dinv[n];
    float ar = dn * us2f(h2[(size_t)n * H2F + f]);
    int e = beg;
    int nfull = (end - beg) >> 3;
    if (nfull > 0) {
        int sn[8];
#pragma unroll
        for (int j = 0; j < 8; ++j) sn[j] = csr[e + j];
        for (int b = 0; b < nfull; ++b) {
            int sc[8];
#pragma unroll
            for (int j = 0; j < 8; ++j) sc[j] = sn[j];
            e += 8;
            if (b + 1 < nfull) {
#pragma unroll
                for (int j = 0; j < 8; ++j) sn[j] = csr[e + j];   // prefetch next batch
            }
            float w0 = dinv[sc[0]], w1 = dinv[sc[1]], w2 = dinv[sc[2]], w3 = dinv[sc[3]];
            float w4 = dinv[sc[4]], w5 = dinv[sc[5]], w6 = dinv[sc[6]], w7 = dinv[sc[7]];
            unsigned short v0 = h2[(size_t)sc[0] * H2F + f];
            unsigned short v1 = h2[(size_t)sc[1] * H2F + f];
            unsigned short v2 = h2[(size_t)sc[2] * H2F + f];
            unsigned short v3 = h2[(size_t)sc[3] * H2F + f];
            unsigned short v4 = h2[(size_t)sc[4] * H2F + f];
            unsigned short v5 = h2[(size_t)sc[5] * H2F + f];
            unsigned short v6 = h2[(size_t)sc[6] * H2F + f];
            unsigned short v7 = h2[(size_t)sc[7] * H2F + f];
            ar += w0 * us2f(v0); ar += w1 * us2f(v1);
            ar += w2 * us2f(v2); ar += w3 * us2f(v3);
            ar += w4 * us2f(v4); ar += w5 * us2f(v5);
            ar += w6 * us2f(v6); ar += w7 * us2f(v7);
        }
    }
    for (; e + 3 < end; e += 4) {
        int s0 = csr[e], s1 = csr[e + 1], s2 = csr[e + 2], s3 = csr[e + 3];
        float w0 = dinv[s0], w1 = dinv[s1], w2 = dinv[s2], w3 = dinv[s3];
        unsigned short v0 = h2[(size_t)s0 * H2F + f];
        unsigned short v1 = h2[(size_t)s1 * H2F + f];
        unsigned short v2 = h2[(size_t)s2 * H2F + f];
        unsigned short v3 = h2[(size_t)s3 * H2F + f];
        ar += w0 * us2f(v0); ar += w1 * us2f(v1);
        ar += w2 * us2f(v2); ar += w3 * us2f(v3);
    }
    for (; e < end; ++e) {
        int s = csr[e];
        ar += dinv[s] * us2f(h2[(size_t)s * H2F + f]);
    }
    ar = ar * dn + ld(b2v, f, isbf);                    // conv2 out (no relu)
    float acc1 = 0.f;
#pragma unroll
    for (int k = 0; k < H2F; ++k)
        acc1 += __shfl(ar, k, 32) * ld(Wf, (size_t)k * H2F + f, isbf);
    float u = fmaxf(acc1 + ld(bfv, f, isbf), 0.f);
    float acc2 = 0.f;
#pragma unroll
    for (int k = 0; k < H2F; ++k)
        acc2 += __shfl(u, k, 32) * ld(Wo, (size_t)k * NCLS + f, isbf);
    float r = acc2 + ld(bov, f, isbf);
    size_t oi = (size_t)n * NCLS + f;
    if (isbf) ((__hip_bfloat16*)out)[oi] = __float2bfloat16(r);
    else      ((float*)out)[oi] = r;
}

extern "C" void kernel_launch(void* const* d_in, const int* in_sizes, int n_in,
                              void* d_out, int out_size, void* d_ws, size_t ws_size,
                              hipStream_t stream) {
    const void* x  = d_in[0];
    const int*  ei = (const int*)d_in[1];
    const void* W1 = d_in[2];
    const void* b1 = d_in[3];
    const void* W2 = d_in[4];
    const void* b2 = d_in[5];
    const void* Wf = d_in[6];
    const void* bf = d_in[7];
    const void* Wo = d_in[8];
    const void* bo = d_in[9];

    // workspace (peak ~48 MB):
    //  deg @0 | rowptr @512K | dinv @1M | flags @1.4M | partial @1.41M | chunkoff @1.42M
    //  aux @2M (12.8M) | csr @15M (12.8M) | h1 @28M (12.8M bf16) | h2 @41M (6.4M bf16)
    char* ws = (char*)d_ws;
    int*            deg      = (int*)  (ws + 0);
    int*            rowptr   = (int*)  (ws + (512u  << 10));
    float*          dinv     = (float*)(ws + (1024u << 10));
    int*            flags    = (int*)  (ws + (1434u << 10));
    int*            partial  = (int*)  (ws + (1444u << 10));
    int*            chunkoff = (int*)  (ws + (1454u << 10));
    int*            aux      = (int*)  (ws + (2u  << 20));
    int*            csr      = (int*)  (ws + (15u << 20));
    unsigned short* h1       = (unsigned short*)(ws + (28u << 20));
    unsigned short* h2       = (unsigned short*)(ws + (41u << 20));

    const int B = 256;

    k_detect<<<1, 64, 0, stream>>>(x, ei, flags);
    hipMemsetAsync(deg, 0, N_NODES * sizeof(int), stream);

    // fused gemm1 + histogram (independent work, interleaved for co-residency)
    k_front<<<NFRONT, B, 0, stream>>>(x, W1, ei, deg, aux, h1, flags);

    k_scanA<<<SCAN_CHUNKS, SCAN_BLOCK, 0, stream>>>(deg, partial, dinv);
    k_scanB<<<1, 64, 0, stream>>>(partial, chunkoff);
    k_scanC<<<SCAN_CHUNKS, SCAN_BLOCK, 0, stream>>>(deg, chunkoff, rowptr);
    k_scatter<<<(N_EDGES / 8 + B - 1) / B, B, 0, stream>>>(ei, aux, rowptr, csr, flags);

    k_agg1gemm2<<<(N_NODES * 64 + B - 1) / B, B, 0, stream>>>(h1, dinv, rowptr, csr,
                                                              b1, W2, h2, flags);
    GCN_51737176048479_kernel<<<(N_NODES * 32 + B - 1) / B, B, 0, stream>>>(
        h2, dinv, rowptr, csr, b2, Wf, bf, Wo, bo, d_out, flags);
}